// Round 1
// baseline (864.690 us; speedup 1.0000x reference)
//
#include <hip/hip_runtime.h>
#include <cstdint>

#define DIN 4096
#define DOUT 4096
#define QMAXF 127.0f

typedef int v4i __attribute__((ext_vector_type(4)));
typedef unsigned int u32;

__device__ __forceinline__ void async16(const void* g, void* l) {
  __builtin_amdgcn_global_load_lds((const __attribute__((address_space(1))) u32*)g,
                                   (__attribute__((address_space(3))) u32*)l,
                                   16, 0, 0);
}

__device__ __forceinline__ int clamp_q(float v) {
  int i = (int)rintf(v);           // v_rndne: round half to even, matches np.round
  return i < -128 ? -128 : (i > 127 ? 127 : i);
}

// --- Kernel 1: ternary f32 weights -> int8 (w values are exactly -1/0/1) ---
__global__ __launch_bounds__(256) void wconvert_kernel(const float* __restrict__ w,
                                                       int8_t* __restrict__ wq) {
  int t = blockIdx.x * 256 + threadIdx.x;
  float4 v = ((const float4*)w)[t];
  int b0 = ((int)v.x) & 255, b1 = ((int)v.y) & 255;
  int b2 = ((int)v.z) & 255, b3 = ((int)v.w) & 255;
  ((int*)wq)[t] = b0 | (b1 << 8) | (b2 << 16) | (b3 << 24);
}

// --- Kernel 2: RMSNorm + per-token absmax int8 quant ---
// One block per token. x row kept in registers (16 f32/thread) across both passes.
__global__ __launch_bounds__(256) void rmsnorm_quant_kernel(
    const float* __restrict__ x, const float* __restrict__ gamma,
    const float* __restrict__ scale_w_ptr, int8_t* __restrict__ xq,
    float* __restrict__ inv_scale) {
  const int token = blockIdx.x;
  const float* xr = x + (size_t)token * DIN;
  const int t = threadIdx.x;

  float4 xv[4], gv[4];
  float ss = 0.f, amax = 0.f;
#pragma unroll
  for (int i = 0; i < 4; ++i) {
    const int idx = (i * 256 + t) * 4;
    xv[i] = *(const float4*)(xr + idx);
    gv[i] = *(const float4*)(gamma + idx);
    ss += xv[i].x * xv[i].x + xv[i].y * xv[i].y + xv[i].z * xv[i].z + xv[i].w * xv[i].w;
    amax = fmaxf(amax, fabsf(xv[i].x * gv[i].x));
    amax = fmaxf(amax, fabsf(xv[i].y * gv[i].y));
    amax = fmaxf(amax, fabsf(xv[i].z * gv[i].z));
    amax = fmaxf(amax, fabsf(xv[i].w * gv[i].w));
  }
#pragma unroll
  for (int o = 32; o > 0; o >>= 1) {
    ss += __shfl_down(ss, o);
    amax = fmaxf(amax, __shfl_down(amax, o));
  }
  __shared__ float s_ss[4], s_am[4];
  const int wave = t >> 6, lane = t & 63;
  if (lane == 0) { s_ss[wave] = ss; s_am[wave] = amax; }
  __syncthreads();
  const float tot = s_ss[0] + s_ss[1] + s_ss[2] + s_ss[3];
  const float mx = fmaxf(fmaxf(s_am[0], s_am[1]), fmaxf(s_am[2], s_am[3]));
  const float rstd = rsqrtf(tot * (1.0f / DIN) + 1e-5f);
  // |xn| = rstd * |x*gamma|  (rstd > 0), so absmax(xn) = rstd * max|x*gamma|
  const float absmax = fmaxf(mx * rstd, 1e-5f);
  const float qscale = rstd * (QMAXF / absmax);   // x*gamma*qscale == xn*scale_x
  if (t == 0) inv_scale[token] = absmax / (QMAXF * scale_w_ptr[0]);

  int* qr = (int*)(xq + (size_t)token * DIN);
#pragma unroll
  for (int i = 0; i < 4; ++i) {
    const int idx4 = i * 256 + t;  // dword index within row
    int b0 = clamp_q(xv[i].x * gv[i].x * qscale) & 255;
    int b1 = clamp_q(xv[i].y * gv[i].y * qscale) & 255;
    int b2 = clamp_q(xv[i].z * gv[i].z * qscale) & 255;
    int b3 = clamp_q(xv[i].w * gv[i].w * qscale) & 255;
    qr[idx4] = b0 | (b1 << 8) | (b2 << 16) | (b3 << 24);
  }
}

// --- Kernel 3: int8 GEMM, 128x128 tile, BK=64, mfma_i32_16x16x64_i8 ---
// A = xq [M][K] row-major, B = wq [N][K] row-major (B^T form), both int8.
// out[m][n] = (float)acc * inv_scale[m] + bias[n]
#define BM 128
#define BN 128
#define BK 64

__global__ __launch_bounds__(256) void gemm_i8_kernel(
    const int8_t* __restrict__ xq, const int8_t* __restrict__ wq,
    const float* __restrict__ inv_scale, const float* __restrict__ bias,
    float* __restrict__ out) {
  __shared__ int8_t As[BM * BK];   // 8 KB, 64 B rows
  __shared__ int8_t Bs[BN * BK];   // 8 KB

  const int t = threadIdx.x;
  const int wave = t >> 6;
  const int lane = t & 63;
  const int m0 = blockIdx.y * BM;
  const int n0 = blockIdx.x * BN;

  // staging: flat LDS offset = i*4096 + t*16 (== wave-uniform base + lane*16)
  const int fl0 = t * 16;
  const int fl1 = 4096 + t * 16;
  const int r0 = fl0 >> 6, c0 = fl0 & 63;   // row, col within tile
  const int r1 = fl1 >> 6;                  // same col

  const int8_t* Ag = xq + (size_t)m0 * DIN;
  const int8_t* Bg = wq + (size_t)n0 * DIN;

  v4i acc[4][4];
#pragma unroll
  for (int mi = 0; mi < 4; ++mi)
#pragma unroll
    for (int ni = 0; ni < 4; ++ni) acc[mi][ni] = (v4i){0, 0, 0, 0};

  const int wm = (wave >> 1) * 64;   // 2x2 wave grid, 64x64 out per wave
  const int wn = (wave & 1) * 64;
  const int fr = lane & 15;          // fragment row (m or n)
  const int fk = (lane >> 4) * 16;   // k byte offset within BK

  for (int k0 = 0; k0 < DIN; k0 += BK) {
    __syncthreads();   // previous tile's ds_reads done before overwrite
    async16(Ag + (size_t)r0 * DIN + k0 + c0, &As[fl0]);
    async16(Ag + (size_t)r1 * DIN + k0 + c0, &As[fl1]);
    async16(Bg + (size_t)r0 * DIN + k0 + c0, &Bs[fl0]);
    async16(Bg + (size_t)r1 * DIN + k0 + c0, &Bs[fl1]);
    __syncthreads();   // compiler drains vmcnt before s_barrier

    v4i a[4], b[4];
#pragma unroll
    for (int i = 0; i < 4; ++i)
      a[i] = *(const v4i*)(&As[(wm + i * 16 + fr) * BK + fk]);
#pragma unroll
    for (int i = 0; i < 4; ++i)
      b[i] = *(const v4i*)(&Bs[(wn + i * 16 + fr) * BK + fk]);
#pragma unroll
    for (int mi = 0; mi < 4; ++mi)
#pragma unroll
      for (int ni = 0; ni < 4; ++ni)
        acc[mi][ni] = __builtin_amdgcn_mfma_i32_16x16x64_i8(a[mi], b[ni], acc[mi][ni], 0, 0, 0);
  }

  // epilogue: C/D layout col = lane&15, row = (lane>>4)*4 + reg
  const int col = lane & 15;
  const int rb = (lane >> 4) * 4;
#pragma unroll
  for (int mi = 0; mi < 4; ++mi) {
    float sc[4];
#pragma unroll
    for (int r = 0; r < 4; ++r) sc[r] = inv_scale[m0 + wm + mi * 16 + rb + r];
#pragma unroll
    for (int ni = 0; ni < 4; ++ni) {
      const int gc = n0 + wn + ni * 16 + col;
      const float bb = bias[gc];
#pragma unroll
      for (int r = 0; r < 4; ++r) {
        const int gr = m0 + wm + mi * 16 + rb + r;
        out[(size_t)gr * DOUT + gc] = (float)acc[mi][ni][r] * sc[r] + bb;
      }
    }
  }
}

extern "C" void kernel_launch(void* const* d_in, const int* in_sizes, int n_in,
                              void* d_out, int out_size, void* d_ws, size_t ws_size,
                              hipStream_t stream) {
  const float* x       = (const float*)d_in[0];
  const float* w       = (const float*)d_in[1];
  const float* scale_w = (const float*)d_in[2];
  const float* gamma   = (const float*)d_in[3];
  const float* bias    = (const float*)d_in[4];
  float* out = (float*)d_out;
  const int M = in_sizes[0] / DIN;   // 16384

  // workspace layout: wq (16 MB) | xq (64 MB) | inv_scale (64 KB)
  int8_t* wq = (int8_t*)d_ws;
  int8_t* xq = wq + (size_t)DOUT * DIN;
  float* inv_scale = (float*)(xq + (size_t)M * DIN);

  hipLaunchKernelGGL(wconvert_kernel, dim3((DOUT * DIN) / (256 * 4)), dim3(256), 0, stream,
                     w, wq);
  hipLaunchKernelGGL(rmsnorm_quant_kernel, dim3(M), dim3(256), 0, stream,
                     x, gamma, scale_w, xq, inv_scale);
  hipLaunchKernelGGL(gemm_i8_kernel, dim3(DOUT / BN, M / BM), dim3(256), 0, stream,
                     xq, wq, inv_scale, bias, out);
}

// Round 2
// 830.285 us; speedup vs baseline: 1.0414x; 1.0414x over previous
//
#include <hip/hip_runtime.h>
#include <cstdint>

#define DIN 4096
#define DOUT 4096
#define QMAXF 127.0f

typedef int v4i __attribute__((ext_vector_type(4)));
typedef unsigned int u32;

__device__ __forceinline__ void async16(const void* g, void* l) {
  __builtin_amdgcn_global_load_lds((const __attribute__((address_space(1))) u32*)g,
                                   (__attribute__((address_space(3))) u32*)l,
                                   16, 0, 0);
}

__device__ __forceinline__ int clamp_q(float v) {
  int i = (int)rintf(v);           // v_rndne: round half to even, matches np.round
  return i < -128 ? -128 : (i > 127 ? 127 : i);
}

// --- Kernel 1: ternary f32 weights -> int8 (w values are exactly -1/0/1) ---
__global__ __launch_bounds__(256) void wconvert_kernel(const float* __restrict__ w,
                                                       int8_t* __restrict__ wq) {
  int t = blockIdx.x * 256 + threadIdx.x;
  float4 v = ((const float4*)w)[t];
  int b0 = ((int)v.x) & 255, b1 = ((int)v.y) & 255;
  int b2 = ((int)v.z) & 255, b3 = ((int)v.w) & 255;
  ((int*)wq)[t] = b0 | (b1 << 8) | (b2 << 16) | (b3 << 24);
}

// --- Kernel 2: RMSNorm + per-token absmax int8 quant ---
__global__ __launch_bounds__(256) void rmsnorm_quant_kernel(
    const float* __restrict__ x, const float* __restrict__ gamma,
    const float* __restrict__ scale_w_ptr, int8_t* __restrict__ xq,
    float* __restrict__ inv_scale) {
  const int token = blockIdx.x;
  const float* xr = x + (size_t)token * DIN;
  const int t = threadIdx.x;

  float4 xv[4], gv[4];
  float ss = 0.f, amax = 0.f;
#pragma unroll
  for (int i = 0; i < 4; ++i) {
    const int idx = (i * 256 + t) * 4;
    xv[i] = *(const float4*)(xr + idx);
    gv[i] = *(const float4*)(gamma + idx);
    ss += xv[i].x * xv[i].x + xv[i].y * xv[i].y + xv[i].z * xv[i].z + xv[i].w * xv[i].w;
    amax = fmaxf(amax, fabsf(xv[i].x * gv[i].x));
    amax = fmaxf(amax, fabsf(xv[i].y * gv[i].y));
    amax = fmaxf(amax, fabsf(xv[i].z * gv[i].z));
    amax = fmaxf(amax, fabsf(xv[i].w * gv[i].w));
  }
#pragma unroll
  for (int o = 32; o > 0; o >>= 1) {
    ss += __shfl_down(ss, o);
    amax = fmaxf(amax, __shfl_down(amax, o));
  }
  __shared__ float s_ss[4], s_am[4];
  const int wave = t >> 6, lane = t & 63;
  if (lane == 0) { s_ss[wave] = ss; s_am[wave] = amax; }
  __syncthreads();
  const float tot = s_ss[0] + s_ss[1] + s_ss[2] + s_ss[3];
  const float mx = fmaxf(fmaxf(s_am[0], s_am[1]), fmaxf(s_am[2], s_am[3]));
  const float rstd = rsqrtf(tot * (1.0f / DIN) + 1e-5f);
  const float absmax = fmaxf(mx * rstd, 1e-5f);
  const float qscale = rstd * (QMAXF / absmax);
  if (t == 0) inv_scale[token] = absmax / (QMAXF * scale_w_ptr[0]);

  int* qr = (int*)(xq + (size_t)token * DIN);
#pragma unroll
  for (int i = 0; i < 4; ++i) {
    const int idx4 = i * 256 + t;
    int b0 = clamp_q(xv[i].x * gv[i].x * qscale) & 255;
    int b1 = clamp_q(xv[i].y * gv[i].y * qscale) & 255;
    int b2 = clamp_q(xv[i].z * gv[i].z * qscale) & 255;
    int b3 = clamp_q(xv[i].w * gv[i].w * qscale) & 255;
    qr[idx4] = b0 | (b1 << 8) | (b2 << 16) | (b3 << 24);
  }
}

// --- Kernel 3: int8 GEMM, 128x128 tile, BK=128, swizzled LDS ---
// LDS layout: logical 16B chunk (row, cb) stored at phys chunk (cb+row)&7
// within the row. Staging (global_load_lds, dest = base + lane*16) permutes
// the GLOBAL source column instead: thread handling phys chunk p reads
// logical cb = (p - row) & 7. Fragment reads: every 8-lane group covers all
// 32 banks -> zero conflicts.
#define BM 128
#define BN 128
#define BK 128

__global__ __launch_bounds__(256) void gemm_i8_kernel(
    const int8_t* __restrict__ xq, const int8_t* __restrict__ wq,
    const float* __restrict__ inv_scale, const float* __restrict__ bias,
    float* __restrict__ out) {
  __shared__ int8_t As[BM * BK];   // 16 KB
  __shared__ int8_t Bs[BN * BK];   // 16 KB

  const int t = threadIdx.x;
  const int wave = t >> 6;
  const int lane = t & 63;
  const int m0 = blockIdx.y * BM;
  const int n0 = blockIdx.x * BN;

  // staging: thread t handles phys chunks p = i*256 + t (i=0..3) of each tile
  int srow[4], scol[4];
#pragma unroll
  for (int i = 0; i < 4; ++i) {
    const int p = i * 256 + t;
    srow[i] = p >> 3;                    // tile row
    scol[i] = ((p - (p >> 3)) & 7) * 16; // logical 16B-chunk byte offset in row
  }

  const int8_t* Ag = xq + (size_t)m0 * DIN;
  const int8_t* Bg = wq + (size_t)n0 * DIN;

  v4i acc[4][4];
#pragma unroll
  for (int mi = 0; mi < 4; ++mi)
#pragma unroll
    for (int ni = 0; ni < 4; ++ni) acc[mi][ni] = (v4i){0, 0, 0, 0};

  const int wm = (wave >> 1) * 64;   // 2x2 wave grid, 64x64 out per wave
  const int wn = (wave & 1) * 64;
  const int fr = lane & 15;          // fragment row (m or n)
  const int q = lane >> 4;           // k quarter

  // fragment LDS byte offsets (swizzled)
  int offA[2][4], offB[2][4];
#pragma unroll
  for (int s = 0; s < 2; ++s)
#pragma unroll
    for (int j = 0; j < 4; ++j) {
      const int sw = ((s * 4 + q + fr) & 7) * 16;
      offA[s][j] = (wm + j * 16 + fr) * BK + sw;
      offB[s][j] = (wn + j * 16 + fr) * BK + sw;
    }

  for (int k0 = 0; k0 < DIN; k0 += BK) {
    __syncthreads();   // previous tile's ds_reads done before overwrite
#pragma unroll
    for (int i = 0; i < 4; ++i)
      async16(Ag + (size_t)srow[i] * DIN + k0 + scol[i], &As[i * 4096 + t * 16]);
#pragma unroll
    for (int i = 0; i < 4; ++i)
      async16(Bg + (size_t)srow[i] * DIN + k0 + scol[i], &Bs[i * 4096 + t * 16]);
    __syncthreads();   // drains vmcnt before barrier

#pragma unroll
    for (int s = 0; s < 2; ++s) {
      v4i a[4], b[4];
#pragma unroll
      for (int j = 0; j < 4; ++j) a[j] = *(const v4i*)(&As[offA[s][j]]);
#pragma unroll
      for (int j = 0; j < 4; ++j) b[j] = *(const v4i*)(&Bs[offB[s][j]]);
#pragma unroll
      for (int mi = 0; mi < 4; ++mi)
#pragma unroll
        for (int ni = 0; ni < 4; ++ni)
          acc[mi][ni] = __builtin_amdgcn_mfma_i32_16x16x64_i8(a[mi], b[ni], acc[mi][ni], 0, 0, 0);
    }
  }

  // epilogue: C/D layout col = lane&15, row = (lane>>4)*4 + reg
  const int col = lane & 15;
  const int rb = (lane >> 4) * 4;
#pragma unroll
  for (int mi = 0; mi < 4; ++mi) {
    float sc[4];
#pragma unroll
    for (int r = 0; r < 4; ++r) sc[r] = inv_scale[m0 + wm + mi * 16 + rb + r];
#pragma unroll
    for (int ni = 0; ni < 4; ++ni) {
      const int gc = n0 + wn + ni * 16 + col;
      const float bb = bias[gc];
#pragma unroll
      for (int r = 0; r < 4; ++r) {
        const int gr = m0 + wm + mi * 16 + rb + r;
        out[(size_t)gr * DOUT + gc] = (float)acc[mi][ni][r] * sc[r] + bb;
      }
    }
  }
}

extern "C" void kernel_launch(void* const* d_in, const int* in_sizes, int n_in,
                              void* d_out, int out_size, void* d_ws, size_t ws_size,
                              hipStream_t stream) {
  const float* x       = (const float*)d_in[0];
  const float* w       = (const float*)d_in[1];
  const float* scale_w = (const float*)d_in[2];
  const float* gamma   = (const float*)d_in[3];
  const float* bias    = (const float*)d_in[4];
  float* out = (float*)d_out;
  const int M = in_sizes[0] / DIN;   // 16384

  // workspace layout: wq (16 MB) | xq (64 MB) | inv_scale (64 KB)
  int8_t* wq = (int8_t*)d_ws;
  int8_t* xq = wq + (size_t)DOUT * DIN;
  float* inv_scale = (float*)(xq + (size_t)M * DIN);

  hipLaunchKernelGGL(wconvert_kernel, dim3((DOUT * DIN) / (256 * 4)), dim3(256), 0, stream,
                     w, wq);
  hipLaunchKernelGGL(rmsnorm_quant_kernel, dim3(M), dim3(256), 0, stream,
                     x, gamma, scale_w, xq, inv_scale);
  hipLaunchKernelGGL(gemm_i8_kernel, dim3(DOUT / BN, M / BM), dim3(256), 0, stream,
                     xq, wq, inv_scale, bias, out);
}